// Round 14
// baseline (3129.877 us; speedup 1.0000x reference)
//
#include <hip/hip_runtime.h>

#define HH 128
constexpr int cN   = 200000;
constexpr int cE   = 800000;
constexpr int cNS  = 400000;
constexpr int cES  = 1600000;
constexpr int cB   = 512;
constexpr int cPPG = 8;
constexpr int cPT  = 4;
constexpr int cNP  = cB * cPPG;     // 4096 patches
constexpr int cNF  = 64;
constexpr int cNE  = 16;
constexpr int cRW  = 16;
constexpr int cPRW = 16;
constexpr int cL   = 4;

typedef __attribute__((ext_vector_type(8))) short s16x8;
typedef __attribute__((ext_vector_type(4))) float f32x4;

__device__ __forceinline__ float b2f(unsigned short b) {
    return __uint_as_float(((unsigned int)b) << 16);
}
__device__ __forceinline__ unsigned short f2b(float f) {
    unsigned int u = __float_as_uint(f);
    return (unsigned short)((u + 0x7fffu + ((u >> 16) & 1u)) >> 16);  // RNE
}

// ---------------- diagnostic ----------------
__global__ void k_diag(float* __restrict__ out, int n, float val) {
    int gid = blockIdx.x * 256 + threadIdx.x;
    if (gid < n) out[gid] = val;
}

__global__ void k_zero_int(int* __restrict__ p, int n) {
    int i = blockIdx.x * 256 + threadIdx.x;
    if (i < n) p[i] = 0;
}
__global__ void k_copy_int(const int* __restrict__ a, int* __restrict__ b, int n) {
    int i = blockIdx.x * 256 + threadIdx.x;
    if (i < n) b[i] = a[i];
}

// ---------------- CSR build ----------------
__global__ void k_hist(const int* __restrict__ dst, int* __restrict__ cnt, int ne) {
    int e = blockIdx.x * 256 + threadIdx.x;
    if (e < ne) atomicAdd(&cnt[dst[e]], 1);
}

__global__ void k_scan_local(const int* __restrict__ cnt, int* __restrict__ rp1,
                             int* __restrict__ bsum, int n) {
    __shared__ int s[256];
    int t = threadIdx.x;
    int i = blockIdx.x * 256 + t;
    s[t] = (i < n) ? cnt[i] : 0;
    __syncthreads();
    for (int off = 1; off < 256; off <<= 1) {
        int u = (t >= off) ? s[t - off] : 0;
        __syncthreads();
        s[t] += u;
        __syncthreads();
    }
    if (i < n) rp1[i] = s[t];
    if (t == 255) bsum[blockIdx.x] = s[255];
}

__global__ void k_scan_bsums(int* __restrict__ bsum, int nb) {
    __shared__ int s[256];
    __shared__ int carry;
    int t = threadIdx.x;
    if (t == 0) carry = 0;
    __syncthreads();
    for (int base = 0; base < nb; base += 256) {
        int i = base + t;
        s[t] = (i < nb) ? bsum[i] : 0;
        __syncthreads();
        for (int off = 1; off < 256; off <<= 1) {
            int u = (t >= off) ? s[t - off] : 0;
            __syncthreads();
            s[t] += u;
            __syncthreads();
        }
        int c = carry;
        if (i < nb) bsum[i] = s[t] + c;
        __syncthreads();
        if (t == 0) carry = c + s[255];
        __syncthreads();
    }
}

__global__ void k_rp_finalize(const int* __restrict__ bsum, int* __restrict__ rp, int n) {
    int i = blockIdx.x * 256 + threadIdx.x;
    if (i == 0) rp[0] = 0;
    if (i < n) {
        int blk = i >> 8;
        rp[i + 1] += blk ? bsum[blk - 1] : 0;
    }
}

__global__ void k_scatter(const int* __restrict__ src, const int* __restrict__ dst,
                          const int* __restrict__ emap, int* __restrict__ cursor,
                          int* __restrict__ srcs, int* __restrict__ ais, int ne) {
    int e = blockIdx.x * 256 + threadIdx.x;
    if (e >= ne) return;
    int d = dst[e];
    int p = atomicAdd(&cursor[d], 1);
    srcs[p] = src[e];
    ais[p] = emap ? emap[e] : e;
}

// ---------------- W -> bf16 MFMA fragments: 4 ctx hi, 4 tgt hi, 4 tgt lo, 3 We-frag sets ----------------
__global__ void k_wfrag_all(const float* __restrict__ cWl, const float* __restrict__ tWl,
                            const float* __restrict__ cWe, const float* __restrict__ tWe,
                            unsigned short* __restrict__ fC, unsigned short* __restrict__ fTH,
                            unsigned short* __restrict__ fTL,
                            unsigned short* __restrict__ wezC,
                            unsigned short* __restrict__ wezTH,
                            unsigned short* __restrict__ wezTL) {
    int g = blockIdx.x * 256 + threadIdx.x;   // 13 * 4096
    int set = g >> 12;
    int r = g & 4095;
    if (set == 12) {
        // We fragments, zero-padded K 16->32: [ct][lane][j]; sub 0=ctx, 1=tgt-hi, 2=tgt-lo
        if (r < 1536) {
            int sub = r >> 9;
            int rr = r & 511;
            int ct = rr >> 6, lane = rr & 63;
            const float* We = (sub == 0) ? cWe : tWe;
            unsigned short* o = (sub == 0) ? wezC : (sub == 1 ? wezTH : wezTL);
#pragma unroll
            for (int j = 0; j < 8; j++) {
                int k = (lane >> 4) * 8 + j;
                unsigned short v = 0;
                if (k < 16) {
                    float w = We[k * HH + ct * 16 + (lane & 15)];
                    unsigned short hi = f2b(w);
                    v = (sub == 2) ? f2b(w - b2f(hi)) : hi;
                }
                o[((size_t)ct * 64 + lane) * 8 + j] = v;
            }
        }
        return;
    }
    int ct = r >> 9, ks = (r >> 6) & 7, lane = r & 63;
    const float* W;
    unsigned short* outp;
    bool lo = false;
    if (set < 4)      { W = cWl + (size_t)set * 2 * HH * HH;       outp = fC  + (size_t)set * 32768; }
    else if (set < 8) { W = tWl + (size_t)(set - 4) * 2 * HH * HH; outp = fTH + (size_t)(set - 4) * 32768; }
    else              { W = tWl + (size_t)(set - 8) * 2 * HH * HH; outp = fTL + (size_t)(set - 8) * 32768; lo = true; }
#pragma unroll
    for (int j = 0; j < 8; j++) {
        float w = W[(size_t)(ks * 32 + (lane >> 4) * 8 + j) * HH + ct * 16 + (lane & 15)];
        unsigned short hi = f2b(w);
        outp[(size_t)r * 8 + j] = lo ? f2b(w - b2f(hi)) : hi;
    }
}

// ---------------- node encoder, 16 nodes/block ----------------
template <bool BF16OUT>
__global__ void __launch_bounds__(256)
k_encode16(const float* __restrict__ x, const float* __restrict__ rw,
           const int* __restrict__ map,
           const float* __restrict__ Win, const float* __restrict__ bin,
           const float* __restrict__ Wrw, const float* __restrict__ brw,
           void* __restrict__ outv) {
    __shared__ float sx[16][cNF];
    __shared__ float srw[16][cRW];
    int t = threadIdx.x;
    int nb = blockIdx.x * 16;
    {
        int n = t >> 4, v = t & 15;
        int node = map ? map[nb + n] : (nb + n);
        ((float4*)&sx[n][0])[v] = ((const float4*)&x[(size_t)node * cNF])[v];
        if (v < 4) ((float4*)&srw[n][0])[v] = ((const float4*)&rw[(size_t)node * cRW])[v];
    }
    int c = t & 127;
    float wcol[cNF], wrcol[cRW];
#pragma unroll
    for (int k = 0; k < cNF; k++) wcol[k] = Win[k * HH + c];
#pragma unroll
    for (int k = 0; k < cRW; k++) wrcol[k] = Wrw[k * HH + c];
    float bsum = bin[c] + brw[c];
    __syncthreads();

#pragma unroll
    for (int p = 0; p < 8; p++) {
        int n = (p * 256 + t) >> 7;
        float acc = bsum;
#pragma unroll
        for (int k = 0; k < cNF; k += 4) {
            float4 s4 = *(const float4*)&sx[n][k];
            acc += s4.x * wcol[k] + s4.y * wcol[k + 1] + s4.z * wcol[k + 2] + s4.w * wcol[k + 3];
        }
#pragma unroll
        for (int k = 0; k < cRW; k += 4) {
            float4 s4 = *(const float4*)&srw[n][k];
            acc += s4.x * wrcol[k] + s4.y * wrcol[k + 1] + s4.z * wrcol[k + 2] + s4.w * wrcol[k + 3];
        }
        size_t oidx = (size_t)(nb + n) * HH + c;
        if (BF16OUT) ((unsigned short*)outv)[oidx] = f2b(acc);
        else         ((float*)outv)[oidx] = acc;
    }
}

// ---------------- ctx layer (round-12 proven): MFMA edge-MLP + edge-parallel agg + bf16 MFMA GEMM ----------------
__global__ void __launch_bounds__(256)
k_layer_ctx(const unsigned short* __restrict__ h_in, unsigned short* __restrict__ h_out,
            const int* __restrict__ rp, const int* __restrict__ srcs,
            const int* __restrict__ ais,
            const float* __restrict__ eattr, const float* __restrict__ ew,
            const unsigned short* __restrict__ wez, const float* __restrict__ be,
            const unsigned short* __restrict__ Wfrag, const float* __restrict__ bias) {
    __shared__ unsigned short pool[8448];   // union: msg[64][130] | At[32][264]
    __shared__ float wsl[64];
    auto msg = (unsigned short (*)[130])pool;
    auto At  = (unsigned short (*)[264])pool;
    int t = threadIdx.x;
    int base = blockIdx.x * 32;
    int lane = t & 63, wv = t >> 6, ar = lane & 15, g4 = lane >> 4;

    s16x8 bez[2];
    float beq[2];
#pragma unroll
    for (int q = 0; q < 2; q++) {
        bez[q] = *(const s16x8*)&wez[((size_t)(2 * wv + q) * 64 + lane) * 8];
        beq[q] = be[(2 * wv + q) * 16 + ar];
    }
    int eblk0 = rp[base], eblk1 = rp[base + 32];
    int prow = t >> 3, pch = (t & 7) * 16;
    int re0 = rp[base + prow], re1 = rp[base + prow + 1];
    float acc[16];
#pragma unroll
    for (int j = 0; j < 16; j++) acc[j] = 0.f;

    for (int cs = eblk0; cs < eblk1; cs += 64) {
        int ce = min(cs + 64, eblk1);
        if (t < 64) {
            int e = cs + t;
            if (e < ce) wsl[t] = ew[ais[e]];
        }
        // phase 1: edge MLP as MFMA [64,16(pad32)] @ [16(pad32),128]
        {
            f32x4 cac[4][2];
#pragma unroll
            for (int rt = 0; rt < 4; rt++)
#pragma unroll
                for (int q = 0; q < 2; q++) cac[rt][q] = (f32x4)(0.f);
#pragma unroll
            for (int rt = 0; rt < 4; rt++) {
                s16x8 af = {0, 0, 0, 0, 0, 0, 0, 0};
                int row = cs + rt * 16 + ar;
                if (g4 < 2 && row < eblk1) {
                    const float* ea = eattr + (size_t)ais[row] * cNE + g4 * 8;
                    float4 lo4 = *(const float4*)ea;
                    float4 hi4 = *(const float4*)(ea + 4);
                    af[0] = (short)f2b(lo4.x); af[1] = (short)f2b(lo4.y);
                    af[2] = (short)f2b(lo4.z); af[3] = (short)f2b(lo4.w);
                    af[4] = (short)f2b(hi4.x); af[5] = (short)f2b(hi4.y);
                    af[6] = (short)f2b(hi4.z); af[7] = (short)f2b(hi4.w);
                }
#pragma unroll
                for (int q = 0; q < 2; q++)
                    cac[rt][q] = __builtin_amdgcn_mfma_f32_16x16x32_bf16(af, bez[q], cac[rt][q], 0, 0, 0);
            }
#pragma unroll
            for (int rt = 0; rt < 4; rt++)
#pragma unroll
                for (int q = 0; q < 2; q++) {
                    int col = (2 * wv + q) * 16 + ar;
#pragma unroll
                    for (int qi = 0; qi < 4; qi++)
                        msg[rt * 16 + g4 * 4 + qi][col] = f2b(fmaxf(cac[rt][q][qi] + beq[q], 0.f));
                }
        }
        __syncthreads();
        // phase 2: thread = (row, 16-ch slice), f32 register accum
        {
            int e0 = max(re0, cs), e1 = min(re1, ce);
            for (int e = e0; e < e1; e++) {
                int sl = e - cs;
                float w = wsl[sl];
                int s = srcs[e];
                const unsigned short* hrow = &h_in[(size_t)s * HH + pch];
#pragma unroll
                for (int j = 0; j < 16; j += 2) {
                    unsigned int hv = *(const unsigned int*)&hrow[j];
                    unsigned int mv = *(const unsigned int*)&msg[sl][pch + j];
                    acc[j]     += (b2f((unsigned short)hv) + b2f((unsigned short)mv)) * w;
                    acc[j + 1] += (b2f((unsigned short)(hv >> 16)) +
                                   b2f((unsigned short)(mv >> 16))) * w;
                }
            }
        }
        __syncthreads();
    }
    // build A-tile (msg dead): agg half from registers, own-h half from global
#pragma unroll
    for (int j = 0; j < 16; j++) At[prow][HH + pch + j] = f2b(acc[j]);
    for (int i = t; i < 512; i += 256) {
        int r = i >> 4, cc = (i & 15) * 8;
        *(s16x8*)&At[r][cc] = *(const s16x8*)&h_in[(size_t)(base + r) * HH + cc];
    }
    __syncthreads();

    // layer GEMM: wave wv -> col-tiles 2wv,2wv+1; row-tiles 0,1; K=256 in 8 steps
    f32x4 ac[2][2];
#pragma unroll
    for (int i1 = 0; i1 < 2; i1++)
#pragma unroll
        for (int i2 = 0; i2 < 2; i2++) ac[i1][i2] = (f32x4)(0.f);
#pragma unroll
    for (int ks = 0; ks < 8; ks++) {
        int ak = ks * 32 + g4 * 8;
        s16x8 a0 = *(const s16x8*)&At[ar][ak];
        s16x8 a1 = *(const s16x8*)&At[16 + ar][ak];
#pragma unroll
        for (int q = 0; q < 2; q++) {
            int ct = 2 * wv + q;
            s16x8 bq = *(const s16x8*)&Wfrag[((size_t)(ct * 8 + ks) * 64 + lane) * 8];
            ac[0][q] = __builtin_amdgcn_mfma_f32_16x16x32_bf16(a0, bq, ac[0][q], 0, 0, 0);
            ac[1][q] = __builtin_amdgcn_mfma_f32_16x16x32_bf16(a1, bq, ac[1][q], 0, 0, 0);
        }
    }
#pragma unroll
    for (int rt = 0; rt < 2; rt++)
#pragma unroll
        for (int q = 0; q < 2; q++) {
            int col = (2 * wv + q) * 16 + ar;
            float bv = bias[col];
#pragma unroll
            for (int qi = 0; qi < 4; qi++) {
                int row = base + rt * 16 + g4 * 4 + qi;
                h_out[(size_t)row * HH + col] = f2b(fmaxf(ac[rt][q][qi] + bv, 0.f));
            }
        }
}

// ---------------- tgt layer: bf16x3 MFMA edge-MLP (f32-accurate msg) + agg + bf16x3 MFMA GEMM ----------------
__global__ void __launch_bounds__(256)
k_layer_tgt(const float* __restrict__ h_in, float* __restrict__ h_out,
            const int* __restrict__ rp, const int* __restrict__ srcs,
            const int* __restrict__ ais,
            const float* __restrict__ eattr, const float* __restrict__ ew,
            const unsigned short* __restrict__ wezH, const unsigned short* __restrict__ wezL,
            const float* __restrict__ be,
            const unsigned short* __restrict__ WfH, const unsigned short* __restrict__ WfL,
            const float* __restrict__ bias) {
    __shared__ unsigned short pool[16896];  // union: msg f32[64][129] | At_hi+At_lo
    __shared__ float wsl[64];
    auto msg  = (float (*)[129])pool;
    auto AtH  = (unsigned short (*)[264])pool;
    auto AtL  = (unsigned short (*)[264])(pool + 8448);
    int t = threadIdx.x;
    int base = blockIdx.x * 32;
    int lane = t & 63, wv = t >> 6, ar = lane & 15, g4 = lane >> 4;

    s16x8 bezH[2], bezL[2];
    float beq[2];
#pragma unroll
    for (int q = 0; q < 2; q++) {
        bezH[q] = *(const s16x8*)&wezH[((size_t)(2 * wv + q) * 64 + lane) * 8];
        bezL[q] = *(const s16x8*)&wezL[((size_t)(2 * wv + q) * 64 + lane) * 8];
        beq[q] = be[(2 * wv + q) * 16 + ar];
    }
    int eblk0 = rp[base], eblk1 = rp[base + 32];
    int prow = t >> 3, pch = (t & 7) * 16;
    int re0 = rp[base + prow], re1 = rp[base + prow + 1];
    float acc[16];
#pragma unroll
    for (int j = 0; j < 16; j++) acc[j] = 0.f;

    for (int cs = eblk0; cs < eblk1; cs += 64) {
        int ce = min(cs + 64, eblk1);
        if (t < 64) {
            int e = cs + t;
            if (e < ce) wsl[t] = ew[ais[e]];
        }
        // phase 1: edge MLP as bf16x3 MFMA (aH*bH + aL*bH + aH*bL), msg f32
        {
            f32x4 cac[4][2];
#pragma unroll
            for (int rt = 0; rt < 4; rt++)
#pragma unroll
                for (int q = 0; q < 2; q++) cac[rt][q] = (f32x4)(0.f);
#pragma unroll
            for (int rt = 0; rt < 4; rt++) {
                s16x8 afH = {0, 0, 0, 0, 0, 0, 0, 0};
                s16x8 afL = {0, 0, 0, 0, 0, 0, 0, 0};
                int row = cs + rt * 16 + ar;
                if (g4 < 2 && row < eblk1) {
                    const float* ea = eattr + (size_t)ais[row] * cNE + g4 * 8;
                    float4 lo4 = *(const float4*)ea;
                    float4 hi4 = *(const float4*)(ea + 4);
                    float vv[8];
                    *(float4*)&vv[0] = lo4;
                    *(float4*)&vv[4] = hi4;
#pragma unroll
                    for (int j = 0; j < 8; j++) {
                        unsigned short hi = f2b(vv[j]);
                        afH[j] = (short)hi;
                        afL[j] = (short)f2b(vv[j] - b2f(hi));
                    }
                }
#pragma unroll
                for (int q = 0; q < 2; q++) {
                    cac[rt][q] = __builtin_amdgcn_mfma_f32_16x16x32_bf16(afH, bezH[q], cac[rt][q], 0, 0, 0);
                    cac[rt][q] = __builtin_amdgcn_mfma_f32_16x16x32_bf16(afL, bezH[q], cac[rt][q], 0, 0, 0);
                    cac[rt][q] = __builtin_amdgcn_mfma_f32_16x16x32_bf16(afH, bezL[q], cac[rt][q], 0, 0, 0);
                }
            }
#pragma unroll
            for (int rt = 0; rt < 4; rt++)
#pragma unroll
                for (int q = 0; q < 2; q++) {
                    int col = (2 * wv + q) * 16 + ar;
#pragma unroll
                    for (int qi = 0; qi < 4; qi++)
                        msg[rt * 16 + g4 * 4 + qi][col] = fmaxf(cac[rt][q][qi] + beq[q], 0.f);
                }
        }
        __syncthreads();
        // phase 2: thread = (row, 16-ch slice), f32 register accum
        {
            int e0 = max(re0, cs), e1 = min(re1, ce);
            for (int e = e0; e < e1; e++) {
                int sl = e - cs;
                float w = wsl[sl];
                int s = srcs[e];
                const float* hrow = &h_in[(size_t)s * HH + pch];
#pragma unroll
                for (int j = 0; j < 16; j += 4) {
                    float4 hv = *(const float4*)&hrow[j];
                    acc[j]     += (hv.x + msg[sl][pch + j])     * w;
                    acc[j + 1] += (hv.y + msg[sl][pch + j + 1]) * w;
                    acc[j + 2] += (hv.z + msg[sl][pch + j + 2]) * w;
                    acc[j + 3] += (hv.w + msg[sl][pch + j + 3]) * w;
                }
            }
        }
        __syncthreads();
    }
    // build hi/lo split A-tile (msg dead)
#pragma unroll
    for (int j = 0; j < 16; j++) {
        float v = acc[j];
        unsigned short hi = f2b(v);
        AtH[prow][HH + pch + j] = hi;
        AtL[prow][HH + pch + j] = f2b(v - b2f(hi));
    }
    for (int i = t; i < 32 * HH; i += 256) {
        int r = i >> 7, c = i & 127;
        float v = h_in[(size_t)(base + r) * HH + c];
        unsigned short hi = f2b(v);
        AtH[r][c] = hi;
        AtL[r][c] = f2b(v - b2f(hi));
    }
    __syncthreads();

    // bf16x3 MFMA layer GEMM
    f32x4 ac[2][2];
#pragma unroll
    for (int i1 = 0; i1 < 2; i1++)
#pragma unroll
        for (int i2 = 0; i2 < 2; i2++) ac[i1][i2] = (f32x4)(0.f);
#pragma unroll
    for (int ks = 0; ks < 8; ks++) {
        int ak = ks * 32 + g4 * 8;
        s16x8 a0h = *(const s16x8*)&AtH[ar][ak];
        s16x8 a1h = *(const s16x8*)&AtH[16 + ar][ak];
        s16x8 a0l = *(const s16x8*)&AtL[ar][ak];
        s16x8 a1l = *(const s16x8*)&AtL[16 + ar][ak];
#pragma unroll
        for (int q = 0; q < 2; q++) {
            int ct = 2 * wv + q;
            size_t fo = ((size_t)(ct * 8 + ks) * 64 + lane) * 8;
            s16x8 bh = *(const s16x8*)&WfH[fo];
            s16x8 bl = *(const s16x8*)&WfL[fo];
            ac[0][q] = __builtin_amdgcn_mfma_f32_16x16x32_bf16(a0h, bh, ac[0][q], 0, 0, 0);
            ac[0][q] = __builtin_amdgcn_mfma_f32_16x16x32_bf16(a0l, bh, ac[0][q], 0, 0, 0);
            ac[0][q] = __builtin_amdgcn_mfma_f32_16x16x32_bf16(a0h, bl, ac[0][q], 0, 0, 0);
            ac[1][q] = __builtin_amdgcn_mfma_f32_16x16x32_bf16(a1h, bh, ac[1][q], 0, 0, 0);
            ac[1][q] = __builtin_amdgcn_mfma_f32_16x16x32_bf16(a1l, bh, ac[1][q], 0, 0, 0);
            ac[1][q] = __builtin_amdgcn_mfma_f32_16x16x32_bf16(a1h, bl, ac[1][q], 0, 0, 0);
        }
    }
#pragma unroll
    for (int rt = 0; rt < 2; rt++)
#pragma unroll
        for (int q = 0; q < 2; q++) {
            int col = (2 * wv + q) * 16 + ar;
            float bv = bias[col];
#pragma unroll
            for (int qi = 0; qi < 4; qi++) {
                int row = base + rt * 16 + g4 * 4 + qi;
                h_out[(size_t)row * HH + col] = fmaxf(ac[rt][q][qi] + bv, 0.f);
            }
        }
}

// ---------------- segmented mean over sorted batch ----------------
__global__ void k_seg_mean_f32(const float* __restrict__ src, const int* __restrict__ map,
                               const int* __restrict__ batch, float* __restrict__ out, int nrows) {
    int b = blockIdx.x;
    int t = threadIdx.x;  // 128
    int lo = 0, hi = nrows;
    while (lo < hi) { int m = (lo + hi) >> 1; if (batch[m] < b) lo = m + 1; else hi = m; }
    int s = lo;
    hi = nrows;
    while (lo < hi) { int m = (lo + hi) >> 1; if (batch[m] < b + 1) lo = m + 1; else hi = m; }
    int e = lo;
    float acc = 0.f;
    for (int r = s; r < e; r++) {
        size_t row = map ? (size_t)map[r] : (size_t)r;
        acc += src[row * HH + t];
    }
    out[(size_t)b * HH + t] = acc / fmaxf((float)(e - s), 1.f);
}

__global__ void k_seg_mean_bf16(const unsigned short* __restrict__ src,
                                const int* __restrict__ batch, float* __restrict__ out, int nrows) {
    int b = blockIdx.x;
    int t = threadIdx.x;  // 128
    int lo = 0, hi = nrows;
    while (lo < hi) { int m = (lo + hi) >> 1; if (batch[m] < b) lo = m + 1; else hi = m; }
    int s = lo;
    hi = nrows;
    while (lo < hi) { int m = (lo + hi) >> 1; if (batch[m] < b + 1) lo = m + 1; else hi = m; }
    int e = lo;
    float acc = 0.f;
    for (int r = s; r < e; r++) acc += b2f(src[(size_t)r * HH + t]);
    out[(size_t)b * HH + t] = acc / fmaxf((float)(e - s), 1.f);
}

// ---------------- head kernels ----------------
__global__ void k_cond(const float* __restrict__ mctx, const float* __restrict__ mtgt,
                       const int* __restrict__ cidx, const int* __restrict__ tgt_idxs,
                       const float* __restrict__ ppe, const float* __restrict__ Wprw,
                       const float* __restrict__ bprw, float* __restrict__ cond,
                       float* __restrict__ out0) {
    int r = blockIdx.x;   // 0..2047
    int t = threadIdx.x;  // 128
    int bg = r >> 2, tt = r & 3;
    int ti = tgt_idxs[bg * cPT + tt] + bg * cPPG;
    int ci = cidx[bg] + bg * cPPG;
    __shared__ float pe[cPRW];
    if (t < cPRW) pe[t] = ppe[(size_t)ti * cPRW + t];
    __syncthreads();
    float acc = bprw[t];
#pragma unroll
    for (int k = 0; k < cPRW; k++) acc += pe[k] * Wprw[k * HH + t];
    cond[(size_t)r * HH + t] = mctx[(size_t)ci * HH + t] + acc;
    out0[(size_t)r * HH + t] = mtgt[(size_t)ti * HH + t];
}

__global__ void k_gemm_h(const float* __restrict__ x, const float* __restrict__ W,
                         const float* __restrict__ b, float* __restrict__ y) {
    int r = blockIdx.x;
    int t = threadIdx.x;  // 128
    __shared__ float xr[HH];
    xr[t] = x[(size_t)r * HH + t];
    __syncthreads();
    float acc = b[t];
#pragma unroll 8
    for (int k = 0; k < HH; k++) acc += xr[k] * W[k * HH + t];
    y[(size_t)r * HH + t] = acc;
}

__global__ void k_bn_stats(const float* __restrict__ x, float* __restrict__ stats, int rows) {
    int c = blockIdx.x;
    int t = threadIdx.x;  // 256
    float s = 0.f, sq = 0.f;
    for (int r = t; r < rows; r += 256) {
        float v = x[(size_t)r * HH + c];
        s += v; sq += v * v;
    }
    __shared__ float bs[256], bq[256];
    bs[t] = s; bq[t] = sq;
    __syncthreads();
    for (int o = 128; o > 0; o >>= 1) {
        if (t < o) { bs[t] += bs[t + o]; bq[t] += bq[t + o]; }
        __syncthreads();
    }
    if (t == 0) {
        float m = bs[0] / rows;
        float var = bq[0] / rows - m * m;
        stats[c] = m;
        stats[HH + c] = rsqrtf(var + 1e-5f);
    }
}

__global__ void k_bn_relu(float* __restrict__ x, const float* __restrict__ stats,
                          const float* __restrict__ g, const float* __restrict__ be, int rows) {
    int gid = blockIdx.x * 256 + threadIdx.x;
    if (gid >= rows * HH) return;
    int c = gid & 127;
    float v = (x[gid] - stats[c]) * stats[HH + c] * g[c] + be[c];
    x[gid] = fmaxf(v, 0.f);
}

// ---------------- CSR build driver ----------------
static void build_csr(const int* src, const int* dst, const int* emap, int nnodes, int ne,
                      int* rp, int* srcs, int* ais, int* cursor, int* bsum,
                      hipStream_t stream) {
    int nb = (nnodes + 255) / 256;
    k_zero_int<<<nb, 256, 0, stream>>>(cursor, nnodes);
    k_hist<<<(ne + 255) / 256, 256, 0, stream>>>(dst, cursor, ne);
    k_scan_local<<<nb, 256, 0, stream>>>(cursor, rp + 1, bsum, nnodes);
    k_scan_bsums<<<1, 256, 0, stream>>>(bsum, nb);
    k_rp_finalize<<<nb, 256, 0, stream>>>(bsum, rp, nnodes);
    k_copy_int<<<nb, 256, 0, stream>>>(rp, cursor, nnodes);
    k_scatter<<<(ne + 255) / 256, 256, 0, stream>>>(src, dst, emap, cursor, srcs, ais, ne);
}

extern "C" void kernel_launch(void* const* d_in, const int* in_sizes, int n_in,
                              void* d_out, int out_size, void* d_ws, size_t ws_size,
                              hipStream_t stream) {
    (void)in_sizes; (void)n_in;
    const float* x      = (const float*)d_in[0];
    const float* rw     = (const float*)d_in[1];
    const int*   eidx   = (const int*)d_in[3];
    const float* eattr  = (const float*)d_in[4];
    const float* ew     = (const float*)d_in[5];
    const float* ppe    = (const float*)d_in[6];
    const int*   nmap   = (const int*)d_in[7];
    const int*   csub   = (const int*)d_in[8];
    const int*   semap  = (const int*)d_in[9];
    const int*   sbatch = (const int*)d_in[10];
    const int*   cidx   = (const int*)d_in[11];
    const int*   tgts   = (const int*)d_in[12];
    const float* Win  = (const float*)d_in[14]; const float* bin  = (const float*)d_in[15];
    const float* Wrw  = (const float*)d_in[16]; const float* brw  = (const float*)d_in[17];
    const float* Wprw = (const float*)d_in[18]; const float* bprw = (const float*)d_in[19];
    const float* cWe  = (const float*)d_in[20]; const float* cbe  = (const float*)d_in[21];
    const float* cWl  = (const float*)d_in[22]; const float* cbl  = (const float*)d_in[23];
    const float* tWe  = (const float*)d_in[24]; const float* tbe  = (const float*)d_in[25];
    const float* tWl  = (const float*)d_in[26]; const float* tbl  = (const float*)d_in[27];
    const float* Wp1  = (const float*)d_in[28]; const float* bp1  = (const float*)d_in[29];
    const float* g1   = (const float*)d_in[30]; const float* be1  = (const float*)d_in[31];
    const float* Wp2  = (const float*)d_in[32]; const float* bp2  = (const float*)d_in[33];
    const float* g2   = (const float*)d_in[34]; const float* be2  = (const float*)d_in[35];
    const float* Wp3  = (const float*)d_in[36]; const float* bp3  = (const float*)d_in[37];
    float* out = (float*)d_out;

    // ---- workspace layout (round-12 proven layout + 3 wez arrays) ----
    const size_t R = (size_t)cN * HH * sizeof(float);  // 102,400,000
    char* base = (char*)d_ws;
    float* R0f = (float*)base;
    float* R1f = (float*)(base + R);
    unsigned short* R0h = (unsigned short*)base;
    unsigned short* R1h = (unsigned short*)(base + R);
    int* ip = (int*)(base + 2 * R);
    int* rp_t  = ip;  ip += cN + 1;
    int* rp_c  = ip;  ip += cNS + 1;
    int* src_t = ip;  ip += cE;
    int* ai_t  = ip;  ip += cE;
    int* src_c = ip;  ip += cES;
    int* ai_c  = ip;  ip += cES;
    int* cursor = ip; ip += cNS;
    int* bsum  = ip;  ip += 2048;
    char* cp = (char*)(((uintptr_t)ip + 15) & ~(uintptr_t)15);
    unsigned short* wfragC  = (unsigned short*)cp;            // 4 x 32768
    unsigned short* wfragTH = wfragC + (size_t)4 * 32768;     // 4 x 32768
    unsigned short* wfragTL = wfragTH + (size_t)4 * 32768;    // 4 x 32768
    unsigned short* wez_c   = wfragTL + (size_t)4 * 32768;    // 4096
    unsigned short* wez_tH  = wez_c + 4096;                   // 4096
    unsigned short* wez_tL  = wez_tH + 4096;                  // 4096
    cp += ((size_t)12 * 32768 + 3 * 4096) * sizeof(unsigned short);
    float* fp  = (float*)cp;
    float* mctx = fp; fp += (size_t)cNP * HH;
    float* mtgt = fp; fp += (size_t)cNP * HH;
    float* bufc = fp; fp += (size_t)2048 * HH;
    float* bufa = fp; fp += (size_t)2048 * HH;
    float* bufb = fp; fp += (size_t)2048 * HH;
    float* stats = fp; fp += 256;
    const size_t need = (size_t)((char*)fp - base);
    if (ws_size < need) {
        k_diag<<<(out_size + 255) / 256, 256, 0, stream>>>(out, out_size,
                                                           (float)(ws_size >> 20));
        return;
    }

    // ---- phase 0: CSRs + W fragments ----
    build_csr(eidx, eidx + cE, nullptr, cN, cE, rp_t, src_t, ai_t, cursor, bsum, stream);
    build_csr(csub, csub + cES, semap, cNS, cES, rp_c, src_c, ai_c, cursor, bsum, stream);
    k_wfrag_all<<<208, 256, 0, stream>>>(cWl, tWl, cWe, tWe, wfragC, wfragTH, wfragTL,
                                         wez_c, wez_tH, wez_tL);

    // ---- phase 1: target branch, f32 ping-pong R0 <-> R1 ----
    k_encode16<false><<<cN / 16, 256, 0, stream>>>(x, rw, nullptr, Win, bin, Wrw, brw, R0f);
    {
        float* hp[2] = { R0f, R1f };
        for (int l = 0; l < cL; l++) {
            k_layer_tgt<<<cN / 32, 256, 0, stream>>>(
                hp[l & 1], hp[(l & 1) ^ 1], rp_t, src_t, ai_t,
                eattr, ew, wez_tH, wez_tL, tbe,
                wfragTH + (size_t)l * 32768, wfragTL + (size_t)l * 32768, tbl + l * HH);
        }
    }
    k_seg_mean_f32<<<cNP, 128, 0, stream>>>(R0f, nmap, sbatch, mtgt, cNS);

    // ---- phase 2: context branch, bf16 ping-pong + MFMA ----
    k_encode16<true><<<cNS / 16, 256, 0, stream>>>(x, rw, nmap, Win, bin, Wrw, brw, R0h);
    {
        unsigned short* hp[2] = { R0h, R1h };
        for (int l = 0; l < cL; l++) {
            k_layer_ctx<<<cNS / 32, 256, 0, stream>>>(
                hp[l & 1], hp[(l & 1) ^ 1], rp_c, src_c, ai_c,
                eattr, ew, wez_c, cbe, wfragC + (size_t)l * 32768, cbl + l * HH);
        }
    }
    k_seg_mean_bf16<<<cNP, 128, 0, stream>>>(R0h, sbatch, mctx, cNS);

    // ---- predictor head ----
    k_cond<<<cB * cPT, 128, 0, stream>>>(mctx, mtgt, cidx, tgts, ppe, Wprw, bprw, bufc, out);
    k_gemm_h<<<2048, 128, 0, stream>>>(bufc, Wp1, bp1, bufa);
    k_bn_stats<<<HH, 256, 0, stream>>>(bufa, stats, 2048);
    k_bn_relu<<<(2048 * HH) / 256, 256, 0, stream>>>(bufa, stats, g1, be1, 2048);
    k_gemm_h<<<2048, 128, 0, stream>>>(bufa, Wp2, bp2, bufb);
    k_bn_stats<<<HH, 256, 0, stream>>>(bufb, stats, 2048);
    k_bn_relu<<<(2048 * HH) / 256, 256, 0, stream>>>(bufb, stats, g2, be2, 2048);
    k_gemm_h<<<2048, 128, 0, stream>>>(bufb, Wp3, bp3, out + (size_t)2048 * HH);
}

// Round 15
// 3020.373 us; speedup vs baseline: 1.0363x; 1.0363x over previous
//
#include <hip/hip_runtime.h>

#define HH 128
constexpr int cN   = 200000;
constexpr int cE   = 800000;
constexpr int cNS  = 400000;
constexpr int cES  = 1600000;
constexpr int cB   = 512;
constexpr int cPPG = 8;
constexpr int cPT  = 4;
constexpr int cNP  = cB * cPPG;     // 4096 patches
constexpr int cNF  = 64;
constexpr int cNE  = 16;
constexpr int cRW  = 16;
constexpr int cPRW = 16;
constexpr int cL   = 4;

typedef __attribute__((ext_vector_type(8))) short s16x8;
typedef __attribute__((ext_vector_type(4))) float f32x4;

__device__ __forceinline__ float b2f(unsigned short b) {
    return __uint_as_float(((unsigned int)b) << 16);
}
__device__ __forceinline__ unsigned short f2b(float f) {
    unsigned int u = __float_as_uint(f);
    return (unsigned short)((u + 0x7fffu + ((u >> 16) & 1u)) >> 16);  // RNE
}

// ---------------- diagnostic ----------------
__global__ void k_diag(float* __restrict__ out, int n, float val) {
    int gid = blockIdx.x * 256 + threadIdx.x;
    if (gid < n) out[gid] = val;
}

__global__ void k_zero_int(int* __restrict__ p, int n) {
    int i = blockIdx.x * 256 + threadIdx.x;
    if (i < n) p[i] = 0;
}
__global__ void k_copy_int(const int* __restrict__ a, int* __restrict__ b, int n) {
    int i = blockIdx.x * 256 + threadIdx.x;
    if (i < n) b[i] = a[i];
}

// ---------------- eattr f32 -> bf16 (one-time; same RNE as per-use conversion) ----------------
__global__ void k_ea16(const float* __restrict__ eattr, unsigned short* __restrict__ ea16, int n) {
    int i = blockIdx.x * 256 + threadIdx.x;
    if (i < n) ea16[i] = f2b(eattr[i]);
}

// ---------------- CSR build ----------------
__global__ void k_hist(const int* __restrict__ dst, int* __restrict__ cnt, int ne) {
    int e = blockIdx.x * 256 + threadIdx.x;
    if (e < ne) atomicAdd(&cnt[dst[e]], 1);
}

__global__ void k_scan_local(const int* __restrict__ cnt, int* __restrict__ rp1,
                             int* __restrict__ bsum, int n) {
    __shared__ int s[256];
    int t = threadIdx.x;
    int i = blockIdx.x * 256 + t;
    s[t] = (i < n) ? cnt[i] : 0;
    __syncthreads();
    for (int off = 1; off < 256; off <<= 1) {
        int u = (t >= off) ? s[t - off] : 0;
        __syncthreads();
        s[t] += u;
        __syncthreads();
    }
    if (i < n) rp1[i] = s[t];
    if (t == 255) bsum[blockIdx.x] = s[255];
}

__global__ void k_scan_bsums(int* __restrict__ bsum, int nb) {
    __shared__ int s[256];
    __shared__ int carry;
    int t = threadIdx.x;
    if (t == 0) carry = 0;
    __syncthreads();
    for (int base = 0; base < nb; base += 256) {
        int i = base + t;
        s[t] = (i < nb) ? bsum[i] : 0;
        __syncthreads();
        for (int off = 1; off < 256; off <<= 1) {
            int u = (t >= off) ? s[t - off] : 0;
            __syncthreads();
            s[t] += u;
            __syncthreads();
        }
        int c = carry;
        if (i < nb) bsum[i] = s[t] + c;
        __syncthreads();
        if (t == 0) carry = c + s[255];
        __syncthreads();
    }
}

__global__ void k_rp_finalize(const int* __restrict__ bsum, int* __restrict__ rp, int n) {
    int i = blockIdx.x * 256 + threadIdx.x;
    if (i == 0) rp[0] = 0;
    if (i < n) {
        int blk = i >> 8;
        rp[i + 1] += blk ? bsum[blk - 1] : 0;
    }
}

__global__ void k_scatter(const int* __restrict__ src, const int* __restrict__ dst,
                          const int* __restrict__ emap, int* __restrict__ cursor,
                          int* __restrict__ srcs, int* __restrict__ ais, int ne) {
    int e = blockIdx.x * 256 + threadIdx.x;
    if (e >= ne) return;
    int d = dst[e];
    int p = atomicAdd(&cursor[d], 1);
    srcs[p] = src[e];
    ais[p] = emap ? emap[e] : e;
}

// ---------------- W -> bf16 MFMA fragments: 4 ctx hi, 4 tgt hi, 4 tgt lo, 3 We-frag sets ----------------
__global__ void k_wfrag_all(const float* __restrict__ cWl, const float* __restrict__ tWl,
                            const float* __restrict__ cWe, const float* __restrict__ tWe,
                            unsigned short* __restrict__ fC, unsigned short* __restrict__ fTH,
                            unsigned short* __restrict__ fTL,
                            unsigned short* __restrict__ wezC,
                            unsigned short* __restrict__ wezTH,
                            unsigned short* __restrict__ wezTL) {
    int g = blockIdx.x * 256 + threadIdx.x;   // 13 * 4096
    int set = g >> 12;
    int r = g & 4095;
    if (set == 12) {
        if (r < 1536) {
            int sub = r >> 9;
            int rr = r & 511;
            int ct = rr >> 6, lane = rr & 63;
            const float* We = (sub == 0) ? cWe : tWe;
            unsigned short* o = (sub == 0) ? wezC : (sub == 1 ? wezTH : wezTL);
#pragma unroll
            for (int j = 0; j < 8; j++) {
                int k = (lane >> 4) * 8 + j;
                unsigned short v = 0;
                if (k < 16) {
                    float w = We[k * HH + ct * 16 + (lane & 15)];
                    unsigned short hi = f2b(w);
                    v = (sub == 2) ? f2b(w - b2f(hi)) : hi;
                }
                o[((size_t)ct * 64 + lane) * 8 + j] = v;
            }
        }
        return;
    }
    int ct = r >> 9, ks = (r >> 6) & 7, lane = r & 63;
    const float* W;
    unsigned short* outp;
    bool lo = false;
    if (set < 4)      { W = cWl + (size_t)set * 2 * HH * HH;       outp = fC  + (size_t)set * 32768; }
    else if (set < 8) { W = tWl + (size_t)(set - 4) * 2 * HH * HH; outp = fTH + (size_t)(set - 4) * 32768; }
    else              { W = tWl + (size_t)(set - 8) * 2 * HH * HH; outp = fTL + (size_t)(set - 8) * 32768; lo = true; }
#pragma unroll
    for (int j = 0; j < 8; j++) {
        float w = W[(size_t)(ks * 32 + (lane >> 4) * 8 + j) * HH + ct * 16 + (lane & 15)];
        unsigned short hi = f2b(w);
        outp[(size_t)r * 8 + j] = lo ? f2b(w - b2f(hi)) : hi;
    }
}

// ---------------- node encoder, 16 nodes/block ----------------
template <bool BF16OUT>
__global__ void __launch_bounds__(256)
k_encode16(const float* __restrict__ x, const float* __restrict__ rw,
           const int* __restrict__ map,
           const float* __restrict__ Win, const float* __restrict__ bin,
           const float* __restrict__ Wrw, const float* __restrict__ brw,
           void* __restrict__ outv) {
    __shared__ float sx[16][cNF];
    __shared__ float srw[16][cRW];
    int t = threadIdx.x;
    int nb = blockIdx.x * 16;
    {
        int n = t >> 4, v = t & 15;
        int node = map ? map[nb + n] : (nb + n);
        ((float4*)&sx[n][0])[v] = ((const float4*)&x[(size_t)node * cNF])[v];
        if (v < 4) ((float4*)&srw[n][0])[v] = ((const float4*)&rw[(size_t)node * cRW])[v];
    }
    int c = t & 127;
    float wcol[cNF], wrcol[cRW];
#pragma unroll
    for (int k = 0; k < cNF; k++) wcol[k] = Win[k * HH + c];
#pragma unroll
    for (int k = 0; k < cRW; k++) wrcol[k] = Wrw[k * HH + c];
    float bsum = bin[c] + brw[c];
    __syncthreads();

#pragma unroll
    for (int p = 0; p < 8; p++) {
        int n = (p * 256 + t) >> 7;
        float acc = bsum;
#pragma unroll
        for (int k = 0; k < cNF; k += 4) {
            float4 s4 = *(const float4*)&sx[n][k];
            acc += s4.x * wcol[k] + s4.y * wcol[k + 1] + s4.z * wcol[k + 2] + s4.w * wcol[k + 3];
        }
#pragma unroll
        for (int k = 0; k < cRW; k += 4) {
            float4 s4 = *(const float4*)&srw[n][k];
            acc += s4.x * wrcol[k] + s4.y * wrcol[k + 1] + s4.z * wrcol[k + 2] + s4.w * wrcol[k + 3];
        }
        size_t oidx = (size_t)(nb + n) * HH + c;
        if (BF16OUT) ((unsigned short*)outv)[oidx] = f2b(acc);
        else         ((float*)outv)[oidx] = acc;
    }
}

// ---------------- ctx layer: MFMA edge-MLP (ea16) + vectorized agg + bf16 MFMA GEMM ----------------
__global__ void __launch_bounds__(256)
k_layer_ctx(const unsigned short* __restrict__ h_in, unsigned short* __restrict__ h_out,
            const int* __restrict__ rp, const int* __restrict__ srcs,
            const int* __restrict__ ais, const unsigned short* __restrict__ ea16,
            const float* __restrict__ ew,
            const unsigned short* __restrict__ wez, const float* __restrict__ be,
            const unsigned short* __restrict__ Wfrag, const float* __restrict__ bias) {
    __shared__ unsigned short pool[8704];   // union: msg[64][136] (17408B) | At[32][264] (16896B)
    __shared__ float wsl[64];
    auto msg = (unsigned short (*)[136])pool;
    auto At  = (unsigned short (*)[264])pool;
    int t = threadIdx.x;
    int base = blockIdx.x * 32;
    int lane = t & 63, wv = t >> 6, ar = lane & 15, g4 = lane >> 4;

    s16x8 bez[2];
    float beq[2];
#pragma unroll
    for (int q = 0; q < 2; q++) {
        bez[q] = *(const s16x8*)&wez[((size_t)(2 * wv + q) * 64 + lane) * 8];
        beq[q] = be[(2 * wv + q) * 16 + ar];
    }
    int eblk0 = rp[base], eblk1 = rp[base + 32];
    int prow = t >> 3, pch = (t & 7) * 16;
    int re0 = rp[base + prow], re1 = rp[base + prow + 1];
    float acc[16];
#pragma unroll
    for (int j = 0; j < 16; j++) acc[j] = 0.f;

    for (int cs = eblk0; cs < eblk1; cs += 64) {
        int ce = min(cs + 64, eblk1);
        if (t < 64) {
            int e = cs + t;
            if (e < ce) wsl[t] = ew[ais[e]];
        }
        // phase 1: edge MLP as MFMA [64,16(pad32)] @ [16(pad32),128], A from ea16
        {
            f32x4 cac[4][2];
#pragma unroll
            for (int rt = 0; rt < 4; rt++)
#pragma unroll
                for (int q = 0; q < 2; q++) cac[rt][q] = (f32x4)(0.f);
#pragma unroll
            for (int rt = 0; rt < 4; rt++) {
                s16x8 af = {0, 0, 0, 0, 0, 0, 0, 0};
                int row = cs + rt * 16 + ar;
                if (g4 < 2 && row < eblk1)
                    af = *(const s16x8*)&ea16[(size_t)ais[row] * cNE + g4 * 8];
#pragma unroll
                for (int q = 0; q < 2; q++)
                    cac[rt][q] = __builtin_amdgcn_mfma_f32_16x16x32_bf16(af, bez[q], cac[rt][q], 0, 0, 0);
            }
#pragma unroll
            for (int rt = 0; rt < 4; rt++)
#pragma unroll
                for (int q = 0; q < 2; q++) {
                    int col = (2 * wv + q) * 16 + ar;
#pragma unroll
                    for (int qi = 0; qi < 4; qi++)
                        msg[rt * 16 + g4 * 4 + qi][col] = f2b(fmaxf(cac[rt][q][qi] + beq[q], 0.f));
                }
        }
        __syncthreads();
        // phase 2: thread = (row, 16-ch slice), vectorized 16B loads, f32 reg accum
        {
            int e0 = max(re0, cs), e1 = min(re1, ce);
            for (int e = e0; e < e1; e++) {
                int sl = e - cs;
                float w = wsl[sl];
                int s = srcs[e];
                const unsigned short* hrow = &h_in[(size_t)s * HH + pch];
                s16x8 hv0 = *(const s16x8*)&hrow[0];
                s16x8 hv1 = *(const s16x8*)&hrow[8];
                s16x8 mv0 = *(const s16x8*)&msg[sl][pch];
                s16x8 mv1 = *(const s16x8*)&msg[sl][pch + 8];
#pragma unroll
                for (int j = 0; j < 8; j++) {
                    acc[j]     += (b2f((unsigned short)hv0[j]) + b2f((unsigned short)mv0[j])) * w;
                    acc[8 + j] += (b2f((unsigned short)hv1[j]) + b2f((unsigned short)mv1[j])) * w;
                }
            }
        }
        __syncthreads();
    }
    // build A-tile (msg dead): agg half from registers, own-h half from global
#pragma unroll
    for (int j = 0; j < 16; j++) At[prow][HH + pch + j] = f2b(acc[j]);
    for (int i = t; i < 512; i += 256) {
        int r = i >> 4, cc = (i & 15) * 8;
        *(s16x8*)&At[r][cc] = *(const s16x8*)&h_in[(size_t)(base + r) * HH + cc];
    }
    __syncthreads();

    // layer GEMM: wave wv -> col-tiles 2wv,2wv+1; row-tiles 0,1; K=256 in 8 steps
    f32x4 ac[2][2];
#pragma unroll
    for (int i1 = 0; i1 < 2; i1++)
#pragma unroll
        for (int i2 = 0; i2 < 2; i2++) ac[i1][i2] = (f32x4)(0.f);
#pragma unroll
    for (int ks = 0; ks < 8; ks++) {
        int ak = ks * 32 + g4 * 8;
        s16x8 a0 = *(const s16x8*)&At[ar][ak];
        s16x8 a1 = *(const s16x8*)&At[16 + ar][ak];
#pragma unroll
        for (int q = 0; q < 2; q++) {
            int ct = 2 * wv + q;
            s16x8 bq = *(const s16x8*)&Wfrag[((size_t)(ct * 8 + ks) * 64 + lane) * 8];
            ac[0][q] = __builtin_amdgcn_mfma_f32_16x16x32_bf16(a0, bq, ac[0][q], 0, 0, 0);
            ac[1][q] = __builtin_amdgcn_mfma_f32_16x16x32_bf16(a1, bq, ac[1][q], 0, 0, 0);
        }
    }
#pragma unroll
    for (int rt = 0; rt < 2; rt++)
#pragma unroll
        for (int q = 0; q < 2; q++) {
            int col = (2 * wv + q) * 16 + ar;
            float bv = bias[col];
#pragma unroll
            for (int qi = 0; qi < 4; qi++) {
                int row = base + rt * 16 + g4 * 4 + qi;
                h_out[(size_t)row * HH + col] = f2b(fmaxf(ac[rt][q][qi] + bv, 0.f));
            }
        }
}

// ---------------- tgt layer: bf16x3 MFMA edge-MLP + vectorized agg + bf16x3 MFMA GEMM ----------------
__global__ void __launch_bounds__(256)
k_layer_tgt(const float* __restrict__ h_in, float* __restrict__ h_out,
            const int* __restrict__ rp, const int* __restrict__ srcs,
            const int* __restrict__ ais,
            const float* __restrict__ eattr, const float* __restrict__ ew,
            const unsigned short* __restrict__ wezH, const unsigned short* __restrict__ wezL,
            const float* __restrict__ be,
            const unsigned short* __restrict__ WfH, const unsigned short* __restrict__ WfL,
            const float* __restrict__ bias) {
    __shared__ unsigned short pool[16896];  // union: msg f32[64][132] (33792B) | At_hi+At_lo (33792B)
    __shared__ float wsl[64];
    auto msg  = (float (*)[132])pool;
    auto AtH  = (unsigned short (*)[264])pool;
    auto AtL  = (unsigned short (*)[264])(pool + 8448);
    int t = threadIdx.x;
    int base = blockIdx.x * 32;
    int lane = t & 63, wv = t >> 6, ar = lane & 15, g4 = lane >> 4;

    s16x8 bezH[2], bezL[2];
    float beq[2];
#pragma unroll
    for (int q = 0; q < 2; q++) {
        bezH[q] = *(const s16x8*)&wezH[((size_t)(2 * wv + q) * 64 + lane) * 8];
        bezL[q] = *(const s16x8*)&wezL[((size_t)(2 * wv + q) * 64 + lane) * 8];
        beq[q] = be[(2 * wv + q) * 16 + ar];
    }
    int eblk0 = rp[base], eblk1 = rp[base + 32];
    int prow = t >> 3, pch = (t & 7) * 16;
    int re0 = rp[base + prow], re1 = rp[base + prow + 1];
    float acc[16];
#pragma unroll
    for (int j = 0; j < 16; j++) acc[j] = 0.f;

    for (int cs = eblk0; cs < eblk1; cs += 64) {
        int ce = min(cs + 64, eblk1);
        if (t < 64) {
            int e = cs + t;
            if (e < ce) wsl[t] = ew[ais[e]];
        }
        // phase 1: edge MLP as bf16x3 MFMA, msg f32
        {
            f32x4 cac[4][2];
#pragma unroll
            for (int rt = 0; rt < 4; rt++)
#pragma unroll
                for (int q = 0; q < 2; q++) cac[rt][q] = (f32x4)(0.f);
#pragma unroll
            for (int rt = 0; rt < 4; rt++) {
                s16x8 afH = {0, 0, 0, 0, 0, 0, 0, 0};
                s16x8 afL = {0, 0, 0, 0, 0, 0, 0, 0};
                int row = cs + rt * 16 + ar;
                if (g4 < 2 && row < eblk1) {
                    const float* ea = eattr + (size_t)ais[row] * cNE + g4 * 8;
                    float4 lo4 = *(const float4*)ea;
                    float4 hi4 = *(const float4*)(ea + 4);
                    float vv[8];
                    *(float4*)&vv[0] = lo4;
                    *(float4*)&vv[4] = hi4;
#pragma unroll
                    for (int j = 0; j < 8; j++) {
                        unsigned short hi = f2b(vv[j]);
                        afH[j] = (short)hi;
                        afL[j] = (short)f2b(vv[j] - b2f(hi));
                    }
                }
#pragma unroll
                for (int q = 0; q < 2; q++) {
                    cac[rt][q] = __builtin_amdgcn_mfma_f32_16x16x32_bf16(afH, bezH[q], cac[rt][q], 0, 0, 0);
                    cac[rt][q] = __builtin_amdgcn_mfma_f32_16x16x32_bf16(afL, bezH[q], cac[rt][q], 0, 0, 0);
                    cac[rt][q] = __builtin_amdgcn_mfma_f32_16x16x32_bf16(afH, bezL[q], cac[rt][q], 0, 0, 0);
                }
            }
#pragma unroll
            for (int rt = 0; rt < 4; rt++)
#pragma unroll
                for (int q = 0; q < 2; q++) {
                    int col = (2 * wv + q) * 16 + ar;
#pragma unroll
                    for (int qi = 0; qi < 4; qi++)
                        msg[rt * 16 + g4 * 4 + qi][col] = fmaxf(cac[rt][q][qi] + beq[q], 0.f);
                }
        }
        __syncthreads();
        // phase 2: vectorized float4 loads, f32 reg accum
        {
            int e0 = max(re0, cs), e1 = min(re1, ce);
            for (int e = e0; e < e1; e++) {
                int sl = e - cs;
                float w = wsl[sl];
                int s = srcs[e];
                const float* hrow = &h_in[(size_t)s * HH + pch];
#pragma unroll
                for (int j = 0; j < 16; j += 4) {
                    float4 hv = *(const float4*)&hrow[j];
                    float4 mv = *(const float4*)&msg[sl][pch + j];
                    acc[j]     += (hv.x + mv.x) * w;
                    acc[j + 1] += (hv.y + mv.y) * w;
                    acc[j + 2] += (hv.z + mv.z) * w;
                    acc[j + 3] += (hv.w + mv.w) * w;
                }
            }
        }
        __syncthreads();
    }
    // build hi/lo split A-tile (msg dead)
#pragma unroll
    for (int j = 0; j < 16; j++) {
        float v = acc[j];
        unsigned short hi = f2b(v);
        AtH[prow][HH + pch + j] = hi;
        AtL[prow][HH + pch + j] = f2b(v - b2f(hi));
    }
    for (int i = t; i < 32 * HH; i += 256) {
        int r = i >> 7, c = i & 127;
        float v = h_in[(size_t)(base + r) * HH + c];
        unsigned short hi = f2b(v);
        AtH[r][c] = hi;
        AtL[r][c] = f2b(v - b2f(hi));
    }
    __syncthreads();

    // bf16x3 MFMA layer GEMM
    f32x4 ac[2][2];
#pragma unroll
    for (int i1 = 0; i1 < 2; i1++)
#pragma unroll
        for (int i2 = 0; i2 < 2; i2++) ac[i1][i2] = (f32x4)(0.f);
#pragma unroll
    for (int ks = 0; ks < 8; ks++) {
        int ak = ks * 32 + g4 * 8;
        s16x8 a0h = *(const s16x8*)&AtH[ar][ak];
        s16x8 a1h = *(const s16x8*)&AtH[16 + ar][ak];
        s16x8 a0l = *(const s16x8*)&AtL[ar][ak];
        s16x8 a1l = *(const s16x8*)&AtL[16 + ar][ak];
#pragma unroll
        for (int q = 0; q < 2; q++) {
            int ct = 2 * wv + q;
            size_t fo = ((size_t)(ct * 8 + ks) * 64 + lane) * 8;
            s16x8 bh = *(const s16x8*)&WfH[fo];
            s16x8 bl = *(const s16x8*)&WfL[fo];
            ac[0][q] = __builtin_amdgcn_mfma_f32_16x16x32_bf16(a0h, bh, ac[0][q], 0, 0, 0);
            ac[0][q] = __builtin_amdgcn_mfma_f32_16x16x32_bf16(a0l, bh, ac[0][q], 0, 0, 0);
            ac[0][q] = __builtin_amdgcn_mfma_f32_16x16x32_bf16(a0h, bl, ac[0][q], 0, 0, 0);
            ac[1][q] = __builtin_amdgcn_mfma_f32_16x16x32_bf16(a1h, bh, ac[1][q], 0, 0, 0);
            ac[1][q] = __builtin_amdgcn_mfma_f32_16x16x32_bf16(a1l, bh, ac[1][q], 0, 0, 0);
            ac[1][q] = __builtin_amdgcn_mfma_f32_16x16x32_bf16(a1h, bl, ac[1][q], 0, 0, 0);
        }
    }
#pragma unroll
    for (int rt = 0; rt < 2; rt++)
#pragma unroll
        for (int q = 0; q < 2; q++) {
            int col = (2 * wv + q) * 16 + ar;
            float bv = bias[col];
#pragma unroll
            for (int qi = 0; qi < 4; qi++) {
                int row = base + rt * 16 + g4 * 4 + qi;
                h_out[(size_t)row * HH + col] = fmaxf(ac[rt][q][qi] + bv, 0.f);
            }
        }
}

// ---------------- segmented mean over sorted batch ----------------
__global__ void k_seg_mean_f32(const float* __restrict__ src, const int* __restrict__ map,
                               const int* __restrict__ batch, float* __restrict__ out, int nrows) {
    int b = blockIdx.x;
    int t = threadIdx.x;  // 128
    int lo = 0, hi = nrows;
    while (lo < hi) { int m = (lo + hi) >> 1; if (batch[m] < b) lo = m + 1; else hi = m; }
    int s = lo;
    hi = nrows;
    while (lo < hi) { int m = (lo + hi) >> 1; if (batch[m] < b + 1) lo = m + 1; else hi = m; }
    int e = lo;
    float acc = 0.f;
    for (int r = s; r < e; r++) {
        size_t row = map ? (size_t)map[r] : (size_t)r;
        acc += src[row * HH + t];
    }
    out[(size_t)b * HH + t] = acc / fmaxf((float)(e - s), 1.f);
}

__global__ void k_seg_mean_bf16(const unsigned short* __restrict__ src,
                                const int* __restrict__ batch, float* __restrict__ out, int nrows) {
    int b = blockIdx.x;
    int t = threadIdx.x;  // 128
    int lo = 0, hi = nrows;
    while (lo < hi) { int m = (lo + hi) >> 1; if (batch[m] < b) lo = m + 1; else hi = m; }
    int s = lo;
    hi = nrows;
    while (lo < hi) { int m = (lo + hi) >> 1; if (batch[m] < b + 1) lo = m + 1; else hi = m; }
    int e = lo;
    float acc = 0.f;
    for (int r = s; r < e; r++) acc += b2f(src[(size_t)r * HH + t]);
    out[(size_t)b * HH + t] = acc / fmaxf((float)(e - s), 1.f);
}

// ---------------- head kernels ----------------
__global__ void k_cond(const float* __restrict__ mctx, const float* __restrict__ mtgt,
                       const int* __restrict__ cidx, const int* __restrict__ tgt_idxs,
                       const float* __restrict__ ppe, const float* __restrict__ Wprw,
                       const float* __restrict__ bprw, float* __restrict__ cond,
                       float* __restrict__ out0) {
    int r = blockIdx.x;   // 0..2047
    int t = threadIdx.x;  // 128
    int bg = r >> 2, tt = r & 3;
    int ti = tgt_idxs[bg * cPT + tt] + bg * cPPG;
    int ci = cidx[bg] + bg * cPPG;
    __shared__ float pe[cPRW];
    if (t < cPRW) pe[t] = ppe[(size_t)ti * cPRW + t];
    __syncthreads();
    float acc = bprw[t];
#pragma unroll
    for (int k = 0; k < cPRW; k++) acc += pe[k] * Wprw[k * HH + t];
    cond[(size_t)r * HH + t] = mctx[(size_t)ci * HH + t] + acc;
    out0[(size_t)r * HH + t] = mtgt[(size_t)ti * HH + t];
}

__global__ void k_gemm_h(const float* __restrict__ x, const float* __restrict__ W,
                         const float* __restrict__ b, float* __restrict__ y) {
    int r = blockIdx.x;
    int t = threadIdx.x;  // 128
    __shared__ float xr[HH];
    xr[t] = x[(size_t)r * HH + t];
    __syncthreads();
    float acc = b[t];
#pragma unroll 8
    for (int k = 0; k < HH; k++) acc += xr[k] * W[k * HH + t];
    y[(size_t)r * HH + t] = acc;
}

__global__ void k_bn_stats(const float* __restrict__ x, float* __restrict__ stats, int rows) {
    int c = blockIdx.x;
    int t = threadIdx.x;  // 256
    float s = 0.f, sq = 0.f;
    for (int r = t; r < rows; r += 256) {
        float v = x[(size_t)r * HH + c];
        s += v; sq += v * v;
    }
    __shared__ float bs[256], bq[256];
    bs[t] = s; bq[t] = sq;
    __syncthreads();
    for (int o = 128; o > 0; o >>= 1) {
        if (t < o) { bs[t] += bs[t + o]; bq[t] += bq[t + o]; }
        __syncthreads();
    }
    if (t == 0) {
        float m = bs[0] / rows;
        float var = bq[0] / rows - m * m;
        stats[c] = m;
        stats[HH + c] = rsqrtf(var + 1e-5f);
    }
}

__global__ void k_bn_relu(float* __restrict__ x, const float* __restrict__ stats,
                          const float* __restrict__ g, const float* __restrict__ be, int rows) {
    int gid = blockIdx.x * 256 + threadIdx.x;
    if (gid >= rows * HH) return;
    int c = gid & 127;
    float v = (x[gid] - stats[c]) * stats[HH + c] * g[c] + be[c];
    x[gid] = fmaxf(v, 0.f);
}

// ---------------- CSR build driver ----------------
static void build_csr(const int* src, const int* dst, const int* emap, int nnodes, int ne,
                      int* rp, int* srcs, int* ais, int* cursor, int* bsum,
                      hipStream_t stream) {
    int nb = (nnodes + 255) / 256;
    k_zero_int<<<nb, 256, 0, stream>>>(cursor, nnodes);
    k_hist<<<(ne + 255) / 256, 256, 0, stream>>>(dst, cursor, ne);
    k_scan_local<<<nb, 256, 0, stream>>>(cursor, rp + 1, bsum, nnodes);
    k_scan_bsums<<<1, 256, 0, stream>>>(bsum, nb);
    k_rp_finalize<<<nb, 256, 0, stream>>>(bsum, rp, nnodes);
    k_copy_int<<<nb, 256, 0, stream>>>(rp, cursor, nnodes);
    k_scatter<<<(ne + 255) / 256, 256, 0, stream>>>(src, dst, emap, cursor, srcs, ais, ne);
}

extern "C" void kernel_launch(void* const* d_in, const int* in_sizes, int n_in,
                              void* d_out, int out_size, void* d_ws, size_t ws_size,
                              hipStream_t stream) {
    (void)in_sizes; (void)n_in;
    const float* x      = (const float*)d_in[0];
    const float* rw     = (const float*)d_in[1];
    const int*   eidx   = (const int*)d_in[3];
    const float* eattr  = (const float*)d_in[4];
    const float* ew     = (const float*)d_in[5];
    const float* ppe    = (const float*)d_in[6];
    const int*   nmap   = (const int*)d_in[7];
    const int*   csub   = (const int*)d_in[8];
    const int*   semap  = (const int*)d_in[9];
    const int*   sbatch = (const int*)d_in[10];
    const int*   cidx   = (const int*)d_in[11];
    const int*   tgts   = (const int*)d_in[12];
    const float* Win  = (const float*)d_in[14]; const float* bin  = (const float*)d_in[15];
    const float* Wrw  = (const float*)d_in[16]; const float* brw  = (const float*)d_in[17];
    const float* Wprw = (const float*)d_in[18]; const float* bprw = (const float*)d_in[19];
    const float* cWe  = (const float*)d_in[20]; const float* cbe  = (const float*)d_in[21];
    const float* cWl  = (const float*)d_in[22]; const float* cbl  = (const float*)d_in[23];
    const float* tWe  = (const float*)d_in[24]; const float* tbe  = (const float*)d_in[25];
    const float* tWl  = (const float*)d_in[26]; const float* tbl  = (const float*)d_in[27];
    const float* Wp1  = (const float*)d_in[28]; const float* bp1  = (const float*)d_in[29];
    const float* g1   = (const float*)d_in[30]; const float* be1  = (const float*)d_in[31];
    const float* Wp2  = (const float*)d_in[32]; const float* bp2  = (const float*)d_in[33];
    const float* g2   = (const float*)d_in[34]; const float* be2  = (const float*)d_in[35];
    const float* Wp3  = (const float*)d_in[36]; const float* bp3  = (const float*)d_in[37];
    float* out = (float*)d_out;

    // ---- workspace layout (round-14 proven layout + ea16) ----
    const size_t R = (size_t)cN * HH * sizeof(float);  // 102,400,000
    char* base = (char*)d_ws;
    float* R0f = (float*)base;
    float* R1f = (float*)(base + R);
    unsigned short* R0h = (unsigned short*)base;
    unsigned short* R1h = (unsigned short*)(base + R);
    int* ip = (int*)(base + 2 * R);
    int* rp_t  = ip;  ip += cN + 1;
    int* rp_c  = ip;  ip += cNS + 1;
    int* src_t = ip;  ip += cE;
    int* ai_t  = ip;  ip += cE;
    int* src_c = ip;  ip += cES;
    int* ai_c  = ip;  ip += cES;
    int* cursor = ip; ip += cNS;
    int* bsum  = ip;  ip += 2048;
    char* cp = (char*)(((uintptr_t)ip + 15) & ~(uintptr_t)15);
    unsigned short* wfragC  = (unsigned short*)cp;            // 4 x 32768
    unsigned short* wfragTH = wfragC + (size_t)4 * 32768;     // 4 x 32768
    unsigned short* wfragTL = wfragTH + (size_t)4 * 32768;    // 4 x 32768
    unsigned short* wez_c   = wfragTL + (size_t)4 * 32768;    // 4096
    unsigned short* wez_tH  = wez_c + 4096;                   // 4096
    unsigned short* wez_tL  = wez_tH + 4096;                  // 4096
    unsigned short* ea16    = wez_tL + 4096;                  // E*16 bf16 = 25.6 MB
    cp += ((size_t)12 * 32768 + 3 * 4096 + (size_t)cE * cNE) * sizeof(unsigned short);
    float* fp  = (float*)cp;
    float* mctx = fp; fp += (size_t)cNP * HH;
    float* mtgt = fp; fp += (size_t)cNP * HH;
    float* bufc = fp; fp += (size_t)2048 * HH;
    float* bufa = fp; fp += (size_t)2048 * HH;
    float* bufb = fp; fp += (size_t)2048 * HH;
    float* stats = fp; fp += 256;
    const size_t need = (size_t)((char*)fp - base);
    if (ws_size < need) {
        k_diag<<<(out_size + 255) / 256, 256, 0, stream>>>(out, out_size,
                                                           (float)(ws_size >> 20));
        return;
    }

    // ---- phase 0: CSRs + W fragments + ea16 ----
    build_csr(eidx, eidx + cE, nullptr, cN, cE, rp_t, src_t, ai_t, cursor, bsum, stream);
    build_csr(csub, csub + cES, semap, cNS, cES, rp_c, src_c, ai_c, cursor, bsum, stream);
    k_wfrag_all<<<208, 256, 0, stream>>>(cWl, tWl, cWe, tWe, wfragC, wfragTH, wfragTL,
                                         wez_c, wez_tH, wez_tL);
    k_ea16<<<(cE * cNE + 255) / 256, 256, 0, stream>>>(eattr, ea16, cE * cNE);

    // ---- phase 1: target branch, f32 ping-pong R0 <-> R1 ----
    k_encode16<false><<<cN / 16, 256, 0, stream>>>(x, rw, nullptr, Win, bin, Wrw, brw, R0f);
    {
        float* hp[2] = { R0f, R1f };
        for (int l = 0; l < cL; l++) {
            k_layer_tgt<<<cN / 32, 256, 0, stream>>>(
                hp[l & 1], hp[(l & 1) ^ 1], rp_t, src_t, ai_t,
                eattr, ew, wez_tH, wez_tL, tbe,
                wfragTH + (size_t)l * 32768, wfragTL + (size_t)l * 32768, tbl + l * HH);
        }
    }
    k_seg_mean_f32<<<cNP, 128, 0, stream>>>(R0f, nmap, sbatch, mtgt, cNS);

    // ---- phase 2: context branch, bf16 ping-pong + MFMA ----
    k_encode16<true><<<cNS / 16, 256, 0, stream>>>(x, rw, nmap, Win, bin, Wrw, brw, R0h);
    {
        unsigned short* hp[2] = { R0h, R1h };
        for (int l = 0; l < cL; l++) {
            k_layer_ctx<<<cNS / 32, 256, 0, stream>>>(
                hp[l & 1], hp[(l & 1) ^ 1], rp_c, src_c, ai_c, ea16,
                ew, wez_c, cbe, wfragC + (size_t)l * 32768, cbl + l * HH);
        }
    }
    k_seg_mean_bf16<<<cNP, 128, 0, stream>>>(R0h, sbatch, mctx, cNS);

    // ---- predictor head ----
    k_cond<<<cB * cPT, 128, 0, stream>>>(mctx, mtgt, cidx, tgts, ppe, Wprw, bprw, bufc, out);
    k_gemm_h<<<2048, 128, 0, stream>>>(bufc, Wp1, bp1, bufa);
    k_bn_stats<<<HH, 256, 0, stream>>>(bufa, stats, 2048);
    k_bn_relu<<<(2048 * HH) / 256, 256, 0, stream>>>(bufa, stats, g1, be1, 2048);
    k_gemm_h<<<2048, 128, 0, stream>>>(bufa, Wp2, bp2, bufb);
    k_bn_stats<<<HH, 256, 0, stream>>>(bufb, stats, 2048);
    k_bn_relu<<<(2048 * HH) / 256, 256, 0, stream>>>(bufb, stats, g2, be2, 2048);
    k_gemm_h<<<2048, 128, 0, stream>>>(bufb, Wp3, bp3, out + (size_t)2048 * HH);
}